// Round 1
// baseline (138.854 us; speedup 1.0000x reference)
//
#include <hip/hip_runtime.h>
#include <hip/hip_bf16.h>

// DecorrelationGradient, KAPPA = 0.5:
//   out = (1-k)*(gram - diag(ms)) + k*(diag(ms) - 1)  ==  0.5*gram - 0.5
// (diag terms cancel exactly at k=0.5). gram = X^T X / N with X [16384, 768] fp32.
//
// Plan:
//   K1: transpose+cast  X [16384,768] f32  ->  XT [768,16384] bf16 (in d_ws)
//       so BOTH Gram operands are k-contiguous (MFMA fragments are k-contiguous
//       per lane; global_load_lds needs lane-contiguous LDS dest).
//   K2: init d_out = -0.5 (d_out is poisoned 0xAA before every launch).
//   K3: m97-style MFMA GEMM, 128x128 tile, BK=32, 16x16x32 bf16 MFMA,
//       K-split 16 -> grid (6,6,16); each block atomicAdds 0.5/N * partial.

#define D_DIM   768
#define K_DIM   16384     // = 8*2048 samples
#define KSPLIT  16
#define KCHUNK  (K_DIM / KSPLIT)   // 1024 -> 32 iters of BK=32

typedef __attribute__((ext_vector_type(8))) short short8;     // bf16 A/B frag (4 VGPRs)
typedef __attribute__((ext_vector_type(4))) float floatx4;    // fp32 C/D frag

typedef __attribute__((address_space(3))) unsigned short lds_ushort;
typedef __attribute__((address_space(1))) const unsigned short g_ushort;

__device__ __forceinline__ void load_lds16(const unsigned short* g, unsigned short* l) {
  // async global->LDS, 16B per lane; LDS dest is wave-uniform base + lane*16
  __builtin_amdgcn_global_load_lds((g_ushort*)g, (lds_ushort*)l, 16, 0, 0);
}

__device__ __forceinline__ unsigned short f2bf(float f) {
  // round-to-nearest-even f32 -> bf16 (inputs are finite gaussians; no NaN path)
  unsigned int u = __float_as_uint(f);
  u += 0x7fffu + ((u >> 16) & 1u);
  return (unsigned short)(u >> 16);
}

// ---------------- K1: transpose + cast -------------------------------------
// x [16384,768] f32 -> xt [768,16384] bf16. 64x64 tiles via LDS.
__global__ __launch_bounds__(256) void transpose_cast_kernel(
    const float* __restrict__ x, unsigned short* __restrict__ xt) {
  __shared__ __align__(16) unsigned short tile[64][72];  // 72: keeps 16B chunks aligned, breaks bank stride
  const int d0 = blockIdx.x * 64;    // 12 tiles over d
  const int n0 = blockIdx.y * 64;    // 256 tiles over n
  const int t  = threadIdx.x;
  const int c4 = t & 15;             // which float4 along d
  const int r  = t >> 4;             // row group along n
#pragma unroll
  for (int i = 0; i < 4; ++i) {
    int row = r + 16 * i;            // n offset in tile
    float4 v = *(const float4*)(x + (size_t)(n0 + row) * D_DIM + d0 + c4 * 4);
    tile[c4 * 4 + 0][row] = f2bf(v.x);
    tile[c4 * 4 + 1][row] = f2bf(v.y);
    tile[c4 * 4 + 2][row] = f2bf(v.z);
    tile[c4 * 4 + 3][row] = f2bf(v.w);
  }
  __syncthreads();
  const int ck = t & 7;              // 16B chunk (8 bf16) along n
  const int rr = t >> 3;             // d offset group
#pragma unroll
  for (int i = 0; i < 2; ++i) {
    int row = rr + 32 * i;           // d offset in tile
    uint4 v = *(const uint4*)&tile[row][ck * 8];
    *(uint4*)(xt + (size_t)(d0 + row) * K_DIM + n0 + ck * 8) = v;
  }
}

// ---------------- K2: init output to -0.5 ----------------------------------
__global__ __launch_bounds__(256) void init_out_kernel(float* __restrict__ out) {
  size_t i = (size_t)blockIdx.x * 256 + threadIdx.x;   // 147456 float4 = 589824 floats
  float4 v = make_float4(-0.5f, -0.5f, -0.5f, -0.5f);
  ((float4*)out)[i] = v;
}

// ---------------- K3: Gram GEMM (m97 structure) ----------------------------
// out[m][n] += scale * sum_k XT[m][k] * XT[n][k], tile 128x128, BK=32.
__global__ __launch_bounds__(256, 2) void gram_gemm_kernel(
    const unsigned short* __restrict__ xt, float* __restrict__ out) {
  __shared__ __align__(16) unsigned short ldsA[128 * 32];  // [row m][k] 8 KiB
  __shared__ __align__(16) unsigned short ldsB[128 * 32];  // [row n][k] 8 KiB

  const int m0 = blockIdx.x * 128;
  const int n0 = blockIdx.y * 128;
  const int kz = blockIdx.z;

  const int t    = threadIdx.x;
  const int wave = t >> 6;
  const int lane = t & 63;
  const int wm   = (wave >> 1) * 64;   // wave's 64x64 quadrant
  const int wn   = (wave & 1) * 64;
  const int lm   = lane & 15;          // m (A) / n (B) within fragment
  const int quad = lane >> 4;          // k-group of 8

  floatx4 zero = {0.f, 0.f, 0.f, 0.f};
  floatx4 acc[4][4];
#pragma unroll
  for (int mi = 0; mi < 4; ++mi)
#pragma unroll
    for (int ni = 0; ni < 4; ++ni) acc[mi][ni] = zero;

  const int kbeg = kz * KCHUNK;

  // staging geometry: tile row = 32 bf16 = 64 B = 4 lanes of 16 B.
  // wave w covers LDS chunks c = 2w, 2w+1 (each 64 lanes * 16 B = 1 KiB).
  for (int it = 0; it < KCHUNK / 32; ++it) {
    const int kb = kbeg + it * 32;
#pragma unroll
    for (int i = 0; i < 2; ++i) {
      const int c     = wave * 2 + i;
      const int flatL = c * 64 + lane;       // 0..511
      const int rrow  = flatL >> 2;          // 0..127 tile row
      const int sub   = flatL & 3;           // 16B piece within row
      const unsigned short* gA = xt + (size_t)(m0 + rrow) * K_DIM + kb + sub * 8;
      const unsigned short* gB = xt + (size_t)(n0 + rrow) * K_DIM + kb + sub * 8;
      load_lds16(gA, &ldsA[flatL * 8]);
      load_lds16(gB, &ldsB[flatL * 8]);
    }
    __syncthreads();   // drains vmcnt(0) for global_load_lds, then barrier

    short8 af[4], bf[4];
#pragma unroll
    for (int mi = 0; mi < 4; ++mi)
      af[mi] = *(const short8*)&ldsA[(wm + mi * 16 + lm) * 32 + quad * 8];
#pragma unroll
    for (int ni = 0; ni < 4; ++ni)
      bf[ni] = *(const short8*)&ldsB[(wn + ni * 16 + lm) * 32 + quad * 8];

#pragma unroll
    for (int mi = 0; mi < 4; ++mi)
#pragma unroll
      for (int ni = 0; ni < 4; ++ni)
        acc[mi][ni] = __builtin_amdgcn_mfma_f32_16x16x32_bf16(
            af[mi], bf[ni], acc[mi][ni], 0, 0, 0);

    __syncthreads();   // protect LDS before next stage overwrites
  }

  // epilogue: C/D layout col=lane&15, row=quad*4+reg (m89/m91-verified)
  const float scale = 0.5f / (float)K_DIM;
#pragma unroll
  for (int mi = 0; mi < 4; ++mi)
#pragma unroll
    for (int ni = 0; ni < 4; ++ni)
#pragma unroll
      for (int r2 = 0; r2 < 4; ++r2) {
        const int grow = m0 + wm + mi * 16 + quad * 4 + r2;
        const int gcol = n0 + wn + ni * 16 + lm;
        atomicAdd(&out[(size_t)grow * D_DIM + gcol], acc[mi][ni][r2] * scale);
      }
}

extern "C" void kernel_launch(void* const* d_in, const int* in_sizes, int n_in,
                              void* d_out, int out_size, void* d_ws, size_t ws_size,
                              hipStream_t stream) {
  const float* x = (const float*)d_in[0];           // [8,2048,768] f32 = [16384,768]
  float* out = (float*)d_out;                       // [768,768] f32
  unsigned short* xt = (unsigned short*)d_ws;       // [768,16384] bf16 (24 MiB)

  transpose_cast_kernel<<<dim3(12, 256), 256, 0, stream>>>(x, xt);
  init_out_kernel<<<576, 256, 0, stream>>>(out);
  gram_gemm_kernel<<<dim3(6, 6, KSPLIT), 256, 0, stream>>>(xt, out);
}